// Round 4
// baseline (915.224 us; speedup 1.0000x reference)
//
#include <hip/hip_runtime.h>
#include <math.h>

#define B_   16
#define S_   4096
#define I_   128
#define HD_  384
#define M_   256
#define K_   384   // M_+I_
#define EPS_ 1e-5f

// ---------------------------------------------------------------- K1: u_pre + BN(u)
__global__ __launch_bounds__(256) void k_upre(const float* __restrict__ x,
                                              const float* __restrict__ wu,
                                              const float* __restrict__ wub,
                                              const float* __restrict__ g_u,
                                              const float* __restrict__ b_u,
                                              const float* __restrict__ mu_u,
                                              const float* __restrict__ var_u,
                                              float* __restrict__ u_bn) {
    __shared__ float w[I_];
    int tid = threadIdx.x;
    if (tid < I_) w[tid] = wu[tid];
    __syncthreads();
    int row = blockIdx.x * 256 + tid;            // 0..65535
    const float4* xr = (const float4*)(x + (size_t)row * I_);
    const float4* w4 = (const float4*)w;
    float4 s4 = {0.f, 0.f, 0.f, 0.f};
    #pragma unroll
    for (int i = 0; i < I_ / 4; i++) {
        float4 xv = xr[i], wv = w4[i];
        s4.x += xv.x * wv.x; s4.y += xv.y * wv.y;
        s4.z += xv.z * wv.z; s4.w += xv.w * wv.w;
    }
    float s = (s4.x + s4.y) + (s4.z + s4.w) + wub[0];
    float rs = 1.0f / sqrtf(var_u[0] + EPS_);
    u_bn[row] = g_u[0] * (s - mu_u[0]) * rs + b_u[0];
}

// ---------------------------------------------------------------- K2: u-LIF (chunk 4, warm-up 128)
__global__ __launch_bounds__(256) void k_ulif(const float* __restrict__ u_bn,
                                              float* __restrict__ u_spk) {
    int b = blockIdx.x, tid = threadIdx.x;
    int chunk = blockIdx.y * 256 + tid;          // 0..1023
    int t0 = chunk * 4;
    int start = t0 - 128; if (start < 0) start = 0;
    const float* ub = u_bn + (size_t)b * S_;
    float v = 0.f;
    for (int t = start; t < t0 + 4; t++) {
        float xv = ub[t];
        v = v + (xv - v) * 0.5f;
        float sp = (v - 1.0f) >= 0.0f ? 1.0f : 0.0f;
        if (t >= t0) u_spk[(size_t)b * S_ + t] = sp;
        v = v * (1.0f - sp);
    }
}

// ---------------------------------------------------------------- K2b: compact sorted spike lists
__global__ __launch_bounds__(256) void k_compact(const float* __restrict__ u_spk,
                                                 int* __restrict__ spk_idx,
                                                 int* __restrict__ spk_cnt) {
    __shared__ int wcnt[4];
    __shared__ int base;
    int b = blockIdx.x, tid = threadIdx.x;
    int lane = tid & 63, w = tid >> 6;
    if (tid == 0) base = 0;
    __syncthreads();
    for (int r = 0; r < 16; r++) {
        int t = r * 256 + tid;
        bool f = u_spk[(size_t)b * S_ + t] > 0.5f;
        unsigned long long bal = __ballot(f);
        int pre = __popcll(bal & (((unsigned long long)1 << lane) - 1ull));
        if (lane == 0) wcnt[w] = __popcll(bal);
        __syncthreads();
        int off = base;
        for (int i = 0; i < w; i++) off += wcnt[i];
        if (f) spk_idx[(size_t)b * S_ + off + pre] = t;
        __syncthreads();
        if (tid == 0) base += wcnt[0] + wcnt[1] + wcnt[2] + wcnt[3];
        __syncthreads();
    }
    if (tid == 0) spk_cnt[b] = base;
}

// ---------------------------------------------------------------- K3: sparse conv + BN(m) -> m_bn [B,M,S]
// LDS: P[0..8192) = zeros(4096) ++ H[ch,:]; P1[k] = P[k+1] (shifted copy, for
// odd-tau alignment). Thread covers t = 2*tid + q + 512*i (q=0..1, i=0..7):
// per spike, per active i-group: ONE aligned ds_read_b64 (canonical stride,
// conflict-free) + 2 adds. Groups with t-range provably in the zero pad are
// skipped (tau>=2048 skips i=0..3). Spike list in LDS with one-ahead prefetch.
__global__ __launch_bounds__(256) void k_conv(const float* __restrict__ H,
                                              const int* __restrict__ spk_idx,
                                              const int* __restrict__ spk_cnt,
                                              const float* __restrict__ g_m,
                                              const float* __restrict__ b_m,
                                              const float* __restrict__ mu_m,
                                              const float* __restrict__ var_m,
                                              float* __restrict__ m_bn) {
    __shared__ float HH[16384];     // dwords [0,8192)=P, [8192,16384)=P1
    __shared__ int spk[S_];
    int bid = blockIdx.x;
    int b = bid >> 8, ch = bid & 255;
    int tid = threadIdx.x;

    float4* HH4 = (float4*)HH;
    const float4* Hv = (const float4*)(H + (size_t)ch * S_);
    // phase 1: P zeros, P data, P1 zero prefix
    for (int i = tid; i < 1024; i += 256) HH4[i] = make_float4(0.f, 0.f, 0.f, 0.f);
    for (int i = tid; i < 1024; i += 256) HH4[1024 + i] = Hv[i];
    for (int i = tid; i < 1024; i += 256) HH4[2048 + i] = make_float4(0.f, 0.f, 0.f, 0.f);
    int n = spk_cnt[b];
    const int* sl = spk_idx + (size_t)b * S_;
    for (int i = tid; i < n; i += 256) spk[i] = sl[i];
    __syncthreads();
    // phase 2: P1 data = P shifted by one dword (P1[4095+k] = H[k])
    for (int k = tid; k < 4096; k += 256) HH[12287 + k] = HH[4096 + k];
    if (tid == 0) HH[16383] = 0.f;
    __syncthreads();

    float2 acc[8];
    #pragma unroll
    for (int i = 0; i < 8; i++) acc[i] = make_float2(0.f, 0.f);
    const float2* HHf2 = (const float2*)HH;

    int tau_next = (n > 0) ? spk[0] : 0;
    for (int j = 0; j < n; j++) {
        int tau = tau_next;
        tau_next = (j + 1 < n) ? spk[j + 1] : 0;
        // f2 index: even tau -> P at dword (4096 + t - tau);
        //           odd tau  -> P1 at dword (8192 + 4095 + t - tau); t = 2*tid + 512*i
        int off = (tau & 1) ? (12287 - tau) : (4096 - tau);
        const float2* hp = HHf2 + tid + (off >> 1);
        if (tau < 2048) {
            #pragma unroll
            for (int i = 0; i < 4; i++) {
                float2 v = hp[256 * i];
                acc[i].x += v.x; acc[i].y += v.y;
            }
        }
        #pragma unroll
        for (int i = 4; i < 8; i++) {
            float2 v = hp[256 * i];
            acc[i].x += v.x; acc[i].y += v.y;
        }
    }

    float g = g_m[ch], bb = b_m[ch], mu = mu_m[ch];
    float rs = 1.0f / sqrtf(var_m[ch] + EPS_);
    float2* out2 = (float2*)(m_bn + ((size_t)b * M_ + ch) * S_);
    #pragma unroll
    for (int i = 0; i < 8; i++) {
        float2 o;
        o.x = g * (acc[i].x - mu) * rs + bb;
        o.y = g * (acc[i].y - mu) * rs + bb;
        out2[tid + 256 * i] = o;
    }
}

// ---------------------------------------------------------------- K5: m-LIF (chunk 256, warm-up 128) -> m_s [B,S,M]
__global__ __launch_bounds__(256) void k_mlif(const float* __restrict__ m_bn,
                                              float* __restrict__ m_s) {
    int b = blockIdx.x;
    int ch = blockIdx.y * 64 + threadIdx.x;
    int c = blockIdx.z * 4 + threadIdx.y;        // 0..15
    int t0 = c * 256;
    int start = t0 - 128; if (start < 0) start = 0;
    const float* src = m_bn + ((size_t)b * M_ + ch) * S_;
    float v = 0.f;
    for (int t = start; t < t0 + 256; t += 4) {
        float4 xv = *(const float4*)(src + t);
        float xs[4] = {xv.x, xv.y, xv.z, xv.w};
        #pragma unroll
        for (int u = 0; u < 4; u++) {
            int t2 = t + u;
            v = v + (xs[u] - v) * 0.5f;
            float sp = (v - 1.0f) >= 0.0f ? 1.0f : 0.0f;
            if (t2 >= t0) m_s[((size_t)b * S_ + t2) * M_ + ch] = sp;
            v = v * (1.0f - sp);
        }
    }
}

// ---------------------------------------------------------------- K6: h GEMM (fp32) 128x128 tile, 8x8/thread
__global__ __launch_bounds__(256) void k_hgemm(const float* __restrict__ m_s,
                                               const float* __restrict__ x,
                                               const float* __restrict__ W,
                                               const float* __restrict__ Wb,
                                               const float* __restrict__ g_h,
                                               const float* __restrict__ b_h,
                                               const float* __restrict__ mu_h,
                                               const float* __restrict__ var_h,
                                               float* __restrict__ h_bn) {
    __shared__ float As[32 * 128];   // As[k][row]
    __shared__ float Bs[32 * 128];   // Bs[k][col]
    int tid = threadIdx.x;
    int row0 = blockIdx.x * 128, col0 = blockIdx.y * 128;
    int tx = tid & 15, ty = tid >> 4;          // micro-tile: 8 cols, 8 rows
    int lrow = tid & 127, half = tid >> 7;     // staging
    float acc[8][8] = {};

    for (int kt = 0; kt < 12; kt++) {
        int kbase = kt * 32 + half * 16;
        const float* Asrc;
        if (kt < 8) Asrc = m_s + (size_t)(row0 + lrow) * M_ + kbase;
        else        Asrc = x   + (size_t)(row0 + lrow) * I_ + (kbase - M_);
        const float* Bsrc = W + (size_t)(col0 + lrow) * K_ + kbase;
        #pragma unroll
        for (int i = 0; i < 4; i++) {
            float4 va = *(const float4*)(Asrc + i * 4);
            float4 vb = *(const float4*)(Bsrc + i * 4);
            int k = half * 16 + i * 4;
            As[(k + 0) * 128 + lrow] = va.x;
            As[(k + 1) * 128 + lrow] = va.y;
            As[(k + 2) * 128 + lrow] = va.z;
            As[(k + 3) * 128 + lrow] = va.w;
            Bs[(k + 0) * 128 + lrow] = vb.x;
            Bs[(k + 1) * 128 + lrow] = vb.y;
            Bs[(k + 2) * 128 + lrow] = vb.z;
            Bs[(k + 3) * 128 + lrow] = vb.w;
        }
        __syncthreads();
        #pragma unroll 4
        for (int kk = 0; kk < 32; kk++) {
            float4 a0 = *(const float4*)&As[kk * 128 + ty * 8];
            float4 a1 = *(const float4*)&As[kk * 128 + ty * 8 + 4];
            float4 b0 = *(const float4*)&Bs[kk * 128 + tx * 8];
            float4 b1 = *(const float4*)&Bs[kk * 128 + tx * 8 + 4];
            float av[8] = {a0.x, a0.y, a0.z, a0.w, a1.x, a1.y, a1.z, a1.w};
            float bv[8] = {b0.x, b0.y, b0.z, b0.w, b1.x, b1.y, b1.z, b1.w};
            #pragma unroll
            for (int r = 0; r < 8; r++)
                #pragma unroll
                for (int c = 0; c < 8; c++)
                    acc[r][c] += av[r] * bv[c];
        }
        __syncthreads();
    }

    int col = col0 + tx * 8;
    float gg[8], bbv[8], mm[8], rs[8], wb[8];
    #pragma unroll
    for (int h = 0; h < 2; h++) {
        float4 g4  = *(const float4*)(g_h  + col + h * 4);
        float4 b4  = *(const float4*)(b_h  + col + h * 4);
        float4 mu4 = *(const float4*)(mu_h + col + h * 4);
        float4 va4 = *(const float4*)(var_h + col + h * 4);
        float4 wb4 = *(const float4*)(Wb   + col + h * 4);
        gg[h*4+0]=g4.x; gg[h*4+1]=g4.y; gg[h*4+2]=g4.z; gg[h*4+3]=g4.w;
        bbv[h*4+0]=b4.x; bbv[h*4+1]=b4.y; bbv[h*4+2]=b4.z; bbv[h*4+3]=b4.w;
        mm[h*4+0]=mu4.x; mm[h*4+1]=mu4.y; mm[h*4+2]=mu4.z; mm[h*4+3]=mu4.w;
        rs[h*4+0]=1.0f/sqrtf(va4.x+EPS_); rs[h*4+1]=1.0f/sqrtf(va4.y+EPS_);
        rs[h*4+2]=1.0f/sqrtf(va4.z+EPS_); rs[h*4+3]=1.0f/sqrtf(va4.w+EPS_);
        wb[h*4+0]=wb4.x; wb[h*4+1]=wb4.y; wb[h*4+2]=wb4.z; wb[h*4+3]=wb4.w;
    }
    #pragma unroll
    for (int r = 0; r < 8; r++) {
        int row = row0 + ty * 8 + r;
        float o[8];
        #pragma unroll
        for (int j = 0; j < 8; j++)
            o[j] = gg[j] * ((acc[r][j] + wb[j]) - mm[j]) * rs[j] + bbv[j];
        float4 o0 = {o[0], o[1], o[2], o[3]};
        float4 o1 = {o[4], o[5], o[6], o[7]};
        *(float4*)(h_bn + (size_t)row * HD_ + col)     = o0;
        *(float4*)(h_bn + (size_t)row * HD_ + col + 4) = o1;
    }
}

// ---------------------------------------------------------------- K7: h-LIF (chunk 256, warm-up 128) -> out
__global__ __launch_bounds__(256) void k_hlif(const float* __restrict__ h_bn,
                                              float* __restrict__ out) {
    int b = blockIdx.x;
    int j = blockIdx.y * 64 + threadIdx.x;
    int c = blockIdx.z * 4 + threadIdx.y;        // 0..15
    int t0 = c * 256;
    int start = t0 - 128; if (start < 0) start = 0;
    float* hn = out + (size_t)B_ * S_ * HD_;
    float v = 0.f;
    for (int t = start; t < t0 + 256; t++) {
        float xv = h_bn[((size_t)b * S_ + t) * HD_ + j];
        v = v + (xv - v) * 0.5f;
        float sp = (v - 1.0f) >= 0.0f ? 1.0f : 0.0f;
        if (t >= t0) {
            out[((size_t)b * S_ + t) * HD_ + j] = sp;
            if (t == S_ - 1) hn[(size_t)b * HD_ + j] = sp;
        }
        v = v * (1.0f - sp);
    }
}

// ---------------------------------------------------------------- launch
extern "C" void kernel_launch(void* const* d_in, const int* in_sizes, int n_in,
                              void* d_out, int out_size, void* d_ws, size_t ws_size,
                              hipStream_t stream) {
    const float* x     = (const float*)d_in[0];
    const float* H     = (const float*)d_in[1];
    const float* Wu    = (const float*)d_in[2];
    const float* Wub   = (const float*)d_in[3];
    const float* Wh    = (const float*)d_in[4];
    const float* Whb   = (const float*)d_in[5];
    const float* g_u   = (const float*)d_in[6];
    const float* b_u   = (const float*)d_in[7];
    const float* mu_u  = (const float*)d_in[8];
    const float* var_u = (const float*)d_in[9];
    const float* g_m   = (const float*)d_in[10];
    const float* b_m   = (const float*)d_in[11];
    const float* mu_m  = (const float*)d_in[12];
    const float* var_m = (const float*)d_in[13];
    const float* g_h   = (const float*)d_in[14];
    const float* b_h   = (const float*)d_in[15];
    const float* mu_h  = (const float*)d_in[16];
    const float* var_h = (const float*)d_in[17];

    float* ws    = (float*)d_ws;
    float* u_bn  = ws;                               // 65536
    float* u_spk = ws + 65536;                       // 65536
    int*   spk_idx = (int*)(ws + 131072);            // 65536 ints
    int*   spk_cnt = (int*)(ws + 196608);            // 16 ints
    float* m_bn  = ws + 200704;                      // 16777216  [B,M,S]
    float* m_s   = m_bn + 16777216;                  // 16777216  [B,S,M]
    float* h_bn  = m_s + 16777216;                   // 25165824  [B*S,HD]

    k_upre<<<dim3(256), dim3(256), 0, stream>>>(x, Wu, Wub, g_u, b_u, mu_u, var_u, u_bn);
    k_ulif<<<dim3(16, 4), dim3(256), 0, stream>>>(u_bn, u_spk);
    k_compact<<<dim3(16), dim3(256), 0, stream>>>(u_spk, spk_idx, spk_cnt);
    k_conv<<<dim3(4096), dim3(256), 0, stream>>>(H, spk_idx, spk_cnt,
                                                 g_m, b_m, mu_m, var_m, m_bn);
    k_mlif<<<dim3(16, 4, 4), dim3(64, 4), 0, stream>>>(m_bn, m_s);
    k_hgemm<<<dim3(512, 3), dim3(256), 0, stream>>>(m_s, x, Wh, Whb,
                                                    g_h, b_h, mu_h, var_h, h_bn);
    k_hlif<<<dim3(16, 6, 4), dim3(64, 4), 0, stream>>>(h_bn, (float*)d_out);
}

// Round 5
// 841.698 us; speedup vs baseline: 1.0874x; 1.0874x over previous
//
#include <hip/hip_runtime.h>
#include <math.h>

#define B_   16
#define S_   4096
#define I_   128
#define HD_  384
#define M_   256
#define K_   384   // M_+I_
#define EPS_ 1e-5f

// ---------------------------------------------------------------- K1: u_pre + BN(u)
__global__ __launch_bounds__(256) void k_upre(const float* __restrict__ x,
                                              const float* __restrict__ wu,
                                              const float* __restrict__ wub,
                                              const float* __restrict__ g_u,
                                              const float* __restrict__ b_u,
                                              const float* __restrict__ mu_u,
                                              const float* __restrict__ var_u,
                                              float* __restrict__ u_bn) {
    __shared__ float w[I_];
    int tid = threadIdx.x;
    if (tid < I_) w[tid] = wu[tid];
    __syncthreads();
    int row = blockIdx.x * 256 + tid;            // 0..65535
    const float4* xr = (const float4*)(x + (size_t)row * I_);
    const float4* w4 = (const float4*)w;
    float4 s4 = {0.f, 0.f, 0.f, 0.f};
    #pragma unroll
    for (int i = 0; i < I_ / 4; i++) {
        float4 xv = xr[i], wv = w4[i];
        s4.x += xv.x * wv.x; s4.y += xv.y * wv.y;
        s4.z += xv.z * wv.z; s4.w += xv.w * wv.w;
    }
    float s = (s4.x + s4.y) + (s4.z + s4.w) + wub[0];
    float rs = 1.0f / sqrtf(var_u[0] + EPS_);
    u_bn[row] = g_u[0] * (s - mu_u[0]) * rs + b_u[0];
}

// ---------------------------------------------------------------- K2: u-LIF (chunk 4, warm-up 128)
__global__ __launch_bounds__(256) void k_ulif(const float* __restrict__ u_bn,
                                              float* __restrict__ u_spk) {
    int b = blockIdx.x, tid = threadIdx.x;
    int chunk = blockIdx.y * 256 + tid;          // 0..1023
    int t0 = chunk * 4;
    int start = t0 - 128; if (start < 0) start = 0;
    const float* ub = u_bn + (size_t)b * S_;
    float v = 0.f;
    for (int t = start; t < t0 + 4; t++) {
        float xv = ub[t];
        v = v + (xv - v) * 0.5f;
        float sp = (v - 1.0f) >= 0.0f ? 1.0f : 0.0f;
        if (t >= t0) u_spk[(size_t)b * S_ + t] = sp;
        v = v * (1.0f - sp);
    }
}

// ---------------------------------------------------------------- K2b: compact sorted spike lists
__global__ __launch_bounds__(256) void k_compact(const float* __restrict__ u_spk,
                                                 int* __restrict__ spk_idx,
                                                 int* __restrict__ spk_cnt) {
    __shared__ int wcnt[4];
    __shared__ int base;
    int b = blockIdx.x, tid = threadIdx.x;
    int lane = tid & 63, w = tid >> 6;
    if (tid == 0) base = 0;
    __syncthreads();
    for (int r = 0; r < 16; r++) {
        int t = r * 256 + tid;
        bool f = u_spk[(size_t)b * S_ + t] > 0.5f;
        unsigned long long bal = __ballot(f);
        int pre = __popcll(bal & (((unsigned long long)1 << lane) - 1ull));
        if (lane == 0) wcnt[w] = __popcll(bal);
        __syncthreads();
        int off = base;
        for (int i = 0; i < w; i++) off += wcnt[i];
        if (f) spk_idx[(size_t)b * S_ + off + pre] = t;
        __syncthreads();
        if (tid == 0) base += wcnt[0] + wcnt[1] + wcnt[2] + wcnt[3];
        __syncthreads();
    }
    if (tid == 0) spk_cnt[b] = base;
}

// ---------------------------------------------------------------- K3: sparse conv + BN(m) -> m_bn [B,M,S]
// Minimal-LDS, max-occupancy version: LDS = 512-float zero pad + H row
// (18 KB -> 8 blocks/CU, 32 waves). Spike list read from global via uniform
// (scalar) loads; group-skip branches are scalar. Thread covers
// t = 512*i + 2*tid (+1), i=0..7: per active group one ds_read2_b32 + 2 adds.
// Group i active iff tau <= 512*i + 511, so in-group lag >= -511 and the
// 512-float pad absorbs all negative lags -> no masking.
__global__ __launch_bounds__(256, 8) void k_conv(const float* __restrict__ H,
                                                 const int* __restrict__ spk_idx,
                                                 const int* __restrict__ spk_cnt,
                                                 const float* __restrict__ g_m,
                                                 const float* __restrict__ b_m,
                                                 const float* __restrict__ mu_m,
                                                 const float* __restrict__ var_m,
                                                 float* __restrict__ m_bn) {
    __shared__ float Hpad[4608];                 // 512 zeros ++ H[ch,0..4096)
    int bid = blockIdx.x;
    int b = bid >> 8, ch = bid & 255;
    int tid = threadIdx.x;

    float4* Hp4 = (float4*)Hpad;
    if (tid < 128) Hp4[tid] = make_float4(0.f, 0.f, 0.f, 0.f);
    const float4* Hv = (const float4*)(H + (size_t)ch * S_);
    for (int i = tid; i < 1024; i += 256) Hp4[128 + i] = Hv[i];
    __syncthreads();

    int n = spk_cnt[b];
    const int* __restrict__ spk_b = spk_idx + (size_t)b * S_;

    float2 acc[8];
    #pragma unroll
    for (int i = 0; i < 8; i++) acc[i] = make_float2(0.f, 0.f);

    const float* tb = Hpad + 512 + 2 * tid;
    int tau_next = (n > 0) ? spk_b[0] : 0;
    for (int j = 0; j < n; j++) {
        int tau = tau_next;
        tau_next = spk_b[j + 1];                 // harmless over-read, unused at j=n-1
        const float* hp = tb - tau;
        if (tau <= 511)  { acc[0].x += hp[0];    acc[0].y += hp[1];    }
        if (tau <= 1023) { acc[1].x += hp[512];  acc[1].y += hp[513];  }
        if (tau <= 1535) { acc[2].x += hp[1024]; acc[2].y += hp[1025]; }
        if (tau <= 2047) { acc[3].x += hp[1536]; acc[3].y += hp[1537]; }
        if (tau <= 2559) { acc[4].x += hp[2048]; acc[4].y += hp[2049]; }
        if (tau <= 3071) { acc[5].x += hp[2560]; acc[5].y += hp[2561]; }
        if (tau <= 3583) { acc[6].x += hp[3072]; acc[6].y += hp[3073]; }
        {                  acc[7].x += hp[3584]; acc[7].y += hp[3585]; }
    }

    float g = g_m[ch], bb = b_m[ch], mu = mu_m[ch];
    float rs = 1.0f / sqrtf(var_m[ch] + EPS_);
    float2* out2 = (float2*)(m_bn + ((size_t)b * M_ + ch) * S_);
    #pragma unroll
    for (int i = 0; i < 8; i++) {
        float2 o;
        o.x = g * (acc[i].x - mu) * rs + bb;
        o.y = g * (acc[i].y - mu) * rs + bb;
        out2[tid + 256 * i] = o;
    }
}

// ---------------------------------------------------------------- K5: m-LIF (chunk 128, warm-up 128) -> m_s [B,S,M]
__global__ __launch_bounds__(256) void k_mlif(const float* __restrict__ m_bn,
                                              float* __restrict__ m_s) {
    int b = blockIdx.x;
    int ch = blockIdx.y * 64 + threadIdx.x;
    int c = blockIdx.z * 4 + threadIdx.y;        // 0..31
    int t0 = c * 128;
    int start = t0 - 128; if (start < 0) start = 0;
    const float* src = m_bn + ((size_t)b * M_ + ch) * S_;
    float v = 0.f;
    for (int t = start; t < t0 + 128; t += 4) {
        float4 xv = *(const float4*)(src + t);
        float xs[4] = {xv.x, xv.y, xv.z, xv.w};
        #pragma unroll
        for (int u = 0; u < 4; u++) {
            int t2 = t + u;
            v = v + (xs[u] - v) * 0.5f;
            float sp = (v - 1.0f) >= 0.0f ? 1.0f : 0.0f;
            if (t2 >= t0) m_s[((size_t)b * S_ + t2) * M_ + ch] = sp;
            v = v * (1.0f - sp);
        }
    }
}

// ---------------------------------------------------------------- K6: h GEMM (fp32) 128x128 tile, 8x8/thread
__global__ __launch_bounds__(256) void k_hgemm(const float* __restrict__ m_s,
                                               const float* __restrict__ x,
                                               const float* __restrict__ W,
                                               const float* __restrict__ Wb,
                                               const float* __restrict__ g_h,
                                               const float* __restrict__ b_h,
                                               const float* __restrict__ mu_h,
                                               const float* __restrict__ var_h,
                                               float* __restrict__ h_bn) {
    __shared__ float As[32 * 128];   // As[k][row]
    __shared__ float Bs[32 * 128];   // Bs[k][col]
    int tid = threadIdx.x;
    int row0 = blockIdx.x * 128, col0 = blockIdx.y * 128;
    int tx = tid & 15, ty = tid >> 4;          // micro-tile: 8 cols, 8 rows
    int lrow = tid & 127, half = tid >> 7;     // staging
    float acc[8][8] = {};

    for (int kt = 0; kt < 12; kt++) {
        int kbase = kt * 32 + half * 16;
        const float* Asrc;
        if (kt < 8) Asrc = m_s + (size_t)(row0 + lrow) * M_ + kbase;
        else        Asrc = x   + (size_t)(row0 + lrow) * I_ + (kbase - M_);
        const float* Bsrc = W + (size_t)(col0 + lrow) * K_ + kbase;
        #pragma unroll
        for (int i = 0; i < 4; i++) {
            float4 va = *(const float4*)(Asrc + i * 4);
            float4 vb = *(const float4*)(Bsrc + i * 4);
            int k = half * 16 + i * 4;
            As[(k + 0) * 128 + lrow] = va.x;
            As[(k + 1) * 128 + lrow] = va.y;
            As[(k + 2) * 128 + lrow] = va.z;
            As[(k + 3) * 128 + lrow] = va.w;
            Bs[(k + 0) * 128 + lrow] = vb.x;
            Bs[(k + 1) * 128 + lrow] = vb.y;
            Bs[(k + 2) * 128 + lrow] = vb.z;
            Bs[(k + 3) * 128 + lrow] = vb.w;
        }
        __syncthreads();
        #pragma unroll 4
        for (int kk = 0; kk < 32; kk++) {
            float4 a0 = *(const float4*)&As[kk * 128 + ty * 8];
            float4 a1 = *(const float4*)&As[kk * 128 + ty * 8 + 4];
            float4 b0 = *(const float4*)&Bs[kk * 128 + tx * 8];
            float4 b1 = *(const float4*)&Bs[kk * 128 + tx * 8 + 4];
            float av[8] = {a0.x, a0.y, a0.z, a0.w, a1.x, a1.y, a1.z, a1.w};
            float bv[8] = {b0.x, b0.y, b0.z, b0.w, b1.x, b1.y, b1.z, b1.w};
            #pragma unroll
            for (int r = 0; r < 8; r++)
                #pragma unroll
                for (int c = 0; c < 8; c++)
                    acc[r][c] += av[r] * bv[c];
        }
        __syncthreads();
    }

    int col = col0 + tx * 8;
    float gg[8], bbv[8], mm[8], rs[8], wb[8];
    #pragma unroll
    for (int h = 0; h < 2; h++) {
        float4 g4  = *(const float4*)(g_h  + col + h * 4);
        float4 b4  = *(const float4*)(b_h  + col + h * 4);
        float4 mu4 = *(const float4*)(mu_h + col + h * 4);
        float4 va4 = *(const float4*)(var_h + col + h * 4);
        float4 wb4 = *(const float4*)(Wb   + col + h * 4);
        gg[h*4+0]=g4.x; gg[h*4+1]=g4.y; gg[h*4+2]=g4.z; gg[h*4+3]=g4.w;
        bbv[h*4+0]=b4.x; bbv[h*4+1]=b4.y; bbv[h*4+2]=b4.z; bbv[h*4+3]=b4.w;
        mm[h*4+0]=mu4.x; mm[h*4+1]=mu4.y; mm[h*4+2]=mu4.z; mm[h*4+3]=mu4.w;
        rs[h*4+0]=1.0f/sqrtf(va4.x+EPS_); rs[h*4+1]=1.0f/sqrtf(va4.y+EPS_);
        rs[h*4+2]=1.0f/sqrtf(va4.z+EPS_); rs[h*4+3]=1.0f/sqrtf(va4.w+EPS_);
        wb[h*4+0]=wb4.x; wb[h*4+1]=wb4.y; wb[h*4+2]=wb4.z; wb[h*4+3]=wb4.w;
    }
    #pragma unroll
    for (int r = 0; r < 8; r++) {
        int row = row0 + ty * 8 + r;
        float o[8];
        #pragma unroll
        for (int j = 0; j < 8; j++)
            o[j] = gg[j] * ((acc[r][j] + wb[j]) - mm[j]) * rs[j] + bbv[j];
        float4 o0 = {o[0], o[1], o[2], o[3]};
        float4 o1 = {o[4], o[5], o[6], o[7]};
        *(float4*)(h_bn + (size_t)row * HD_ + col)     = o0;
        *(float4*)(h_bn + (size_t)row * HD_ + col + 4) = o1;
    }
}

// ---------------------------------------------------------------- K7: h-LIF (chunk 128, warm-up 128) -> out
__global__ __launch_bounds__(256) void k_hlif(const float* __restrict__ h_bn,
                                              float* __restrict__ out) {
    int b = blockIdx.x;
    int j = blockIdx.y * 64 + threadIdx.x;
    int c = blockIdx.z * 4 + threadIdx.y;        // 0..31
    int t0 = c * 128;
    int start = t0 - 128; if (start < 0) start = 0;
    float* hn = out + (size_t)B_ * S_ * HD_;
    float v = 0.f;
    for (int t = start; t < t0 + 128; t++) {
        float xv = h_bn[((size_t)b * S_ + t) * HD_ + j];
        v = v + (xv - v) * 0.5f;
        float sp = (v - 1.0f) >= 0.0f ? 1.0f : 0.0f;
        if (t >= t0) {
            out[((size_t)b * S_ + t) * HD_ + j] = sp;
            if (t == S_ - 1) hn[(size_t)b * HD_ + j] = sp;
        }
        v = v * (1.0f - sp);
    }
}

// ---------------------------------------------------------------- launch
extern "C" void kernel_launch(void* const* d_in, const int* in_sizes, int n_in,
                              void* d_out, int out_size, void* d_ws, size_t ws_size,
                              hipStream_t stream) {
    const float* x     = (const float*)d_in[0];
    const float* H     = (const float*)d_in[1];
    const float* Wu    = (const float*)d_in[2];
    const float* Wub   = (const float*)d_in[3];
    const float* Wh    = (const float*)d_in[4];
    const float* Whb   = (const float*)d_in[5];
    const float* g_u   = (const float*)d_in[6];
    const float* b_u   = (const float*)d_in[7];
    const float* mu_u  = (const float*)d_in[8];
    const float* var_u = (const float*)d_in[9];
    const float* g_m   = (const float*)d_in[10];
    const float* b_m   = (const float*)d_in[11];
    const float* mu_m  = (const float*)d_in[12];
    const float* var_m = (const float*)d_in[13];
    const float* g_h   = (const float*)d_in[14];
    const float* b_h   = (const float*)d_in[15];
    const float* mu_h  = (const float*)d_in[16];
    const float* var_h = (const float*)d_in[17];

    float* ws    = (float*)d_ws;
    float* u_bn  = ws;                               // 65536
    float* u_spk = ws + 65536;                       // 65536
    int*   spk_idx = (int*)(ws + 131072);            // 65536 ints
    int*   spk_cnt = (int*)(ws + 196608);            // 16 ints
    float* m_bn  = ws + 200704;                      // 16777216  [B,M,S]
    float* m_s   = m_bn + 16777216;                  // 16777216  [B,S,M]
    float* h_bn  = m_s + 16777216;                   // 25165824  [B*S,HD]

    k_upre<<<dim3(256), dim3(256), 0, stream>>>(x, Wu, Wub, g_u, b_u, mu_u, var_u, u_bn);
    k_ulif<<<dim3(16, 4), dim3(256), 0, stream>>>(u_bn, u_spk);
    k_compact<<<dim3(16), dim3(256), 0, stream>>>(u_spk, spk_idx, spk_cnt);
    k_conv<<<dim3(4096), dim3(256), 0, stream>>>(H, spk_idx, spk_cnt,
                                                 g_m, b_m, mu_m, var_m, m_bn);
    k_mlif<<<dim3(16, 4, 8), dim3(64, 4), 0, stream>>>(m_bn, m_s);
    k_hgemm<<<dim3(512, 3), dim3(256), 0, stream>>>(m_s, x, Wh, Whb,
                                                    g_h, b_h, mu_h, var_h, h_bn);
    k_hlif<<<dim3(16, 6, 8), dim3(64, 4), 0, stream>>>(h_bn, (float*)d_out);
}

// Round 6
// 707.900 us; speedup vs baseline: 1.2929x; 1.1890x over previous
//
#include <hip/hip_runtime.h>
#include <math.h>

#define B_   16
#define S_   4096
#define I_   128
#define HD_  384
#define M_   256
#define K_   384   // M_+I_
#define EPS_ 1e-5f

// ---------------------------------------------------------------- K1: u_pre + BN(u)
__global__ __launch_bounds__(256) void k_upre(const float* __restrict__ x,
                                              const float* __restrict__ wu,
                                              const float* __restrict__ wub,
                                              const float* __restrict__ g_u,
                                              const float* __restrict__ b_u,
                                              const float* __restrict__ mu_u,
                                              const float* __restrict__ var_u,
                                              float* __restrict__ u_bn) {
    __shared__ float w[I_];
    int tid = threadIdx.x;
    if (tid < I_) w[tid] = wu[tid];
    __syncthreads();
    int row = blockIdx.x * 256 + tid;            // 0..65535
    const float4* xr = (const float4*)(x + (size_t)row * I_);
    const float4* w4 = (const float4*)w;
    float4 s4 = {0.f, 0.f, 0.f, 0.f};
    #pragma unroll
    for (int i = 0; i < I_ / 4; i++) {
        float4 xv = xr[i], wv = w4[i];
        s4.x += xv.x * wv.x; s4.y += xv.y * wv.y;
        s4.z += xv.z * wv.z; s4.w += xv.w * wv.w;
    }
    float s = (s4.x + s4.y) + (s4.z + s4.w) + wub[0];
    float rs = 1.0f / sqrtf(var_u[0] + EPS_);
    u_bn[row] = g_u[0] * (s - mu_u[0]) * rs + b_u[0];
}

// ---------------------------------------------------------------- K2: u-LIF (chunk 4, warm-up 128)
__global__ __launch_bounds__(256) void k_ulif(const float* __restrict__ u_bn,
                                              float* __restrict__ u_spk) {
    int b = blockIdx.x, tid = threadIdx.x;
    int chunk = blockIdx.y * 256 + tid;          // 0..1023
    int t0 = chunk * 4;
    int start = t0 - 128; if (start < 0) start = 0;
    const float* ub = u_bn + (size_t)b * S_;
    float v = 0.f;
    for (int t = start; t < t0 + 4; t++) {
        float xv = ub[t];
        v = v + (xv - v) * 0.5f;
        float sp = (v - 1.0f) >= 0.0f ? 1.0f : 0.0f;
        if (t >= t0) u_spk[(size_t)b * S_ + t] = sp;
        v = v * (1.0f - sp);
    }
}

// ---------------------------------------------------------------- K2b: compact sorted spike lists
__global__ __launch_bounds__(256) void k_compact(const float* __restrict__ u_spk,
                                                 int* __restrict__ spk_idx,
                                                 int* __restrict__ spk_cnt) {
    __shared__ int wcnt[4];
    __shared__ int base;
    int b = blockIdx.x, tid = threadIdx.x;
    int lane = tid & 63, w = tid >> 6;
    if (tid == 0) base = 0;
    __syncthreads();
    for (int r = 0; r < 16; r++) {
        int t = r * 256 + tid;
        bool f = u_spk[(size_t)b * S_ + t] > 0.5f;
        unsigned long long bal = __ballot(f);
        int pre = __popcll(bal & (((unsigned long long)1 << lane) - 1ull));
        if (lane == 0) wcnt[w] = __popcll(bal);
        __syncthreads();
        int off = base;
        for (int i = 0; i < w; i++) off += wcnt[i];
        if (f) spk_idx[(size_t)b * S_ + off + pre] = t;
        __syncthreads();
        if (tid == 0) base += wcnt[0] + wcnt[1] + wcnt[2] + wcnt[3];
        __syncthreads();
    }
    if (tid == 0) spk_cnt[b] = base;
}

// ---------------------------------------------------------------- K3: sparse conv + BN(m) -> m_bn [B,M,S]
// Stride-1 lane mapping (t = tid + 256*i, 16 groups): every LDS access is 64
// consecutive dwords -> conflict-free. Groups read in pairs 512 dwords apart
// (ds_read2st64 merge pattern). Spike list is SORTED: partition into 8
// tau-segments (tau>>9 == g); segment g touches exactly pairs k>=g -> zero
// per-spike branches. 512-float zero pad absorbs negative in-pair lags.
// LDS 18.5 KB -> 8 blocks/CU (32 waves).
template<int G>
__device__ __forceinline__ void conv_seg(const int* __restrict__ spk_b,
                                         const int* seg, int tid,
                                         const float* __restrict__ Hpad,
                                         float* acc) {
    int jend = seg[G + 1];
    for (int j = seg[G]; j < jend; j++) {
        int tau = spk_b[j];
        int c = 512 + tid - tau;
        #pragma unroll
        for (int k = G; k < 8; k++) {
            acc[2 * k]     += Hpad[c + 512 * k];
            acc[2 * k + 1] += Hpad[c + 512 * k + 256];
        }
    }
}

__global__ __launch_bounds__(256, 8) void k_conv(const float* __restrict__ H,
                                                 const int* __restrict__ spk_idx,
                                                 const int* __restrict__ spk_cnt,
                                                 const float* __restrict__ g_m,
                                                 const float* __restrict__ b_m,
                                                 const float* __restrict__ mu_m,
                                                 const float* __restrict__ var_m,
                                                 float* __restrict__ m_bn) {
    __shared__ float Hpad[4608];                 // 512 zeros ++ H[ch,0..4096)
    __shared__ int seg[9];
    int bid = blockIdx.x;
    int b = bid >> 8, ch = bid & 255;
    int tid = threadIdx.x;

    float4* Hp4 = (float4*)Hpad;
    if (tid < 128) Hp4[tid] = make_float4(0.f, 0.f, 0.f, 0.f);
    const float4* Hv = (const float4*)(H + (size_t)ch * S_);
    for (int i = tid; i < 1024; i += 256) Hp4[128 + i] = Hv[i];

    int n = spk_cnt[b];
    const int* __restrict__ spk_b = spk_idx + (size_t)b * S_;
    if (tid < 8) {                               // seg[g] = first j with tau >= 512g
        int target = 512 * tid;
        int lo = 0, hi = n;
        while (lo < hi) {
            int mid = (lo + hi) >> 1;
            if (spk_b[mid] < target) lo = mid + 1; else hi = mid;
        }
        seg[tid] = lo;
    }
    if (tid == 8) seg[8] = n;
    __syncthreads();

    float acc[16];
    #pragma unroll
    for (int i = 0; i < 16; i++) acc[i] = 0.f;

    conv_seg<0>(spk_b, seg, tid, Hpad, acc);
    conv_seg<1>(spk_b, seg, tid, Hpad, acc);
    conv_seg<2>(spk_b, seg, tid, Hpad, acc);
    conv_seg<3>(spk_b, seg, tid, Hpad, acc);
    conv_seg<4>(spk_b, seg, tid, Hpad, acc);
    conv_seg<5>(spk_b, seg, tid, Hpad, acc);
    conv_seg<6>(spk_b, seg, tid, Hpad, acc);
    conv_seg<7>(spk_b, seg, tid, Hpad, acc);

    float g = g_m[ch], bb = b_m[ch], mu = mu_m[ch];
    float rs = 1.0f / sqrtf(var_m[ch] + EPS_);
    float* out = m_bn + ((size_t)b * M_ + ch) * S_;
    #pragma unroll
    for (int i = 0; i < 16; i++)
        out[tid + 256 * i] = g * (acc[i] - mu) * rs + bb;
}

// ---------------------------------------------------------------- K5: m-LIF (chunk 128, warm-up 128) -> m_s [B,S,M]
__global__ __launch_bounds__(256) void k_mlif(const float* __restrict__ m_bn,
                                              float* __restrict__ m_s) {
    int b = blockIdx.x;
    int ch = blockIdx.y * 64 + threadIdx.x;
    int c = blockIdx.z * 4 + threadIdx.y;        // 0..31
    int t0 = c * 128;
    int start = t0 - 128; if (start < 0) start = 0;
    const float* src = m_bn + ((size_t)b * M_ + ch) * S_;
    float v = 0.f;
    for (int t = start; t < t0 + 128; t += 4) {
        float4 xv = *(const float4*)(src + t);
        float xs[4] = {xv.x, xv.y, xv.z, xv.w};
        #pragma unroll
        for (int u = 0; u < 4; u++) {
            int t2 = t + u;
            v = v + (xs[u] - v) * 0.5f;
            float sp = (v - 1.0f) >= 0.0f ? 1.0f : 0.0f;
            if (t2 >= t0) m_s[((size_t)b * S_ + t2) * M_ + ch] = sp;
            v = v * (1.0f - sp);
        }
    }
}

// ---------------------------------------------------------------- K6: h GEMM (fp32) 128x128 tile, 8x8/thread
__global__ __launch_bounds__(256) void k_hgemm(const float* __restrict__ m_s,
                                               const float* __restrict__ x,
                                               const float* __restrict__ W,
                                               const float* __restrict__ Wb,
                                               const float* __restrict__ g_h,
                                               const float* __restrict__ b_h,
                                               const float* __restrict__ mu_h,
                                               const float* __restrict__ var_h,
                                               float* __restrict__ h_bn) {
    __shared__ float As[32 * 128];   // As[k][row]
    __shared__ float Bs[32 * 128];   // Bs[k][col]
    int tid = threadIdx.x;
    int row0 = blockIdx.x * 128, col0 = blockIdx.y * 128;
    int tx = tid & 15, ty = tid >> 4;          // micro-tile: 8 cols, 8 rows
    int lrow = tid & 127, half = tid >> 7;     // staging
    float acc[8][8] = {};

    for (int kt = 0; kt < 12; kt++) {
        int kbase = kt * 32 + half * 16;
        const float* Asrc;
        if (kt < 8) Asrc = m_s + (size_t)(row0 + lrow) * M_ + kbase;
        else        Asrc = x   + (size_t)(row0 + lrow) * I_ + (kbase - M_);
        const float* Bsrc = W + (size_t)(col0 + lrow) * K_ + kbase;
        #pragma unroll
        for (int i = 0; i < 4; i++) {
            float4 va = *(const float4*)(Asrc + i * 4);
            float4 vb = *(const float4*)(Bsrc + i * 4);
            int k = half * 16 + i * 4;
            As[(k + 0) * 128 + lrow] = va.x;
            As[(k + 1) * 128 + lrow] = va.y;
            As[(k + 2) * 128 + lrow] = va.z;
            As[(k + 3) * 128 + lrow] = va.w;
            Bs[(k + 0) * 128 + lrow] = vb.x;
            Bs[(k + 1) * 128 + lrow] = vb.y;
            Bs[(k + 2) * 128 + lrow] = vb.z;
            Bs[(k + 3) * 128 + lrow] = vb.w;
        }
        __syncthreads();
        #pragma unroll 4
        for (int kk = 0; kk < 32; kk++) {
            float4 a0 = *(const float4*)&As[kk * 128 + ty * 8];
            float4 a1 = *(const float4*)&As[kk * 128 + ty * 8 + 4];
            float4 b0 = *(const float4*)&Bs[kk * 128 + tx * 8];
            float4 b1 = *(const float4*)&Bs[kk * 128 + tx * 8 + 4];
            float av[8] = {a0.x, a0.y, a0.z, a0.w, a1.x, a1.y, a1.z, a1.w};
            float bv[8] = {b0.x, b0.y, b0.z, b0.w, b1.x, b1.y, b1.z, b1.w};
            #pragma unroll
            for (int r = 0; r < 8; r++)
                #pragma unroll
                for (int c = 0; c < 8; c++)
                    acc[r][c] += av[r] * bv[c];
        }
        __syncthreads();
    }

    int col = col0 + tx * 8;
    float gg[8], bbv[8], mm[8], rs[8], wb[8];
    #pragma unroll
    for (int h = 0; h < 2; h++) {
        float4 g4  = *(const float4*)(g_h  + col + h * 4);
        float4 b4  = *(const float4*)(b_h  + col + h * 4);
        float4 mu4 = *(const float4*)(mu_h + col + h * 4);
        float4 va4 = *(const float4*)(var_h + col + h * 4);
        float4 wb4 = *(const float4*)(Wb   + col + h * 4);
        gg[h*4+0]=g4.x; gg[h*4+1]=g4.y; gg[h*4+2]=g4.z; gg[h*4+3]=g4.w;
        bbv[h*4+0]=b4.x; bbv[h*4+1]=b4.y; bbv[h*4+2]=b4.z; bbv[h*4+3]=b4.w;
        mm[h*4+0]=mu4.x; mm[h*4+1]=mu4.y; mm[h*4+2]=mu4.z; mm[h*4+3]=mu4.w;
        rs[h*4+0]=1.0f/sqrtf(va4.x+EPS_); rs[h*4+1]=1.0f/sqrtf(va4.y+EPS_);
        rs[h*4+2]=1.0f/sqrtf(va4.z+EPS_); rs[h*4+3]=1.0f/sqrtf(va4.w+EPS_);
        wb[h*4+0]=wb4.x; wb[h*4+1]=wb4.y; wb[h*4+2]=wb4.z; wb[h*4+3]=wb4.w;
    }
    #pragma unroll
    for (int r = 0; r < 8; r++) {
        int row = row0 + ty * 8 + r;
        float o[8];
        #pragma unroll
        for (int j = 0; j < 8; j++)
            o[j] = gg[j] * ((acc[r][j] + wb[j]) - mm[j]) * rs[j] + bbv[j];
        float4 o0 = {o[0], o[1], o[2], o[3]};
        float4 o1 = {o[4], o[5], o[6], o[7]};
        *(float4*)(h_bn + (size_t)row * HD_ + col)     = o0;
        *(float4*)(h_bn + (size_t)row * HD_ + col + 4) = o1;
    }
}

// ---------------------------------------------------------------- K7: h-LIF (chunk 128, warm-up 128) -> out
__global__ __launch_bounds__(256) void k_hlif(const float* __restrict__ h_bn,
                                              float* __restrict__ out) {
    int b = blockIdx.x;
    int j = blockIdx.y * 64 + threadIdx.x;
    int c = blockIdx.z * 4 + threadIdx.y;        // 0..31
    int t0 = c * 128;
    int start = t0 - 128; if (start < 0) start = 0;
    float* hn = out + (size_t)B_ * S_ * HD_;
    float v = 0.f;
    for (int t = start; t < t0 + 128; t++) {
        float xv = h_bn[((size_t)b * S_ + t) * HD_ + j];
        v = v + (xv - v) * 0.5f;
        float sp = (v - 1.0f) >= 0.0f ? 1.0f : 0.0f;
        if (t >= t0) {
            out[((size_t)b * S_ + t) * HD_ + j] = sp;
            if (t == S_ - 1) hn[(size_t)b * HD_ + j] = sp;
        }
        v = v * (1.0f - sp);
    }
}

// ---------------------------------------------------------------- launch
extern "C" void kernel_launch(void* const* d_in, const int* in_sizes, int n_in,
                              void* d_out, int out_size, void* d_ws, size_t ws_size,
                              hipStream_t stream) {
    const float* x     = (const float*)d_in[0];
    const float* H     = (const float*)d_in[1];
    const float* Wu    = (const float*)d_in[2];
    const float* Wub   = (const float*)d_in[3];
    const float* Wh    = (const float*)d_in[4];
    const float* Whb   = (const float*)d_in[5];
    const float* g_u   = (const float*)d_in[6];
    const float* b_u   = (const float*)d_in[7];
    const float* mu_u  = (const float*)d_in[8];
    const float* var_u = (const float*)d_in[9];
    const float* g_m   = (const float*)d_in[10];
    const float* b_m   = (const float*)d_in[11];
    const float* mu_m  = (const float*)d_in[12];
    const float* var_m = (const float*)d_in[13];
    const float* g_h   = (const float*)d_in[14];
    const float* b_h   = (const float*)d_in[15];
    const float* mu_h  = (const float*)d_in[16];
    const float* var_h = (const float*)d_in[17];

    float* ws    = (float*)d_ws;
    float* u_bn  = ws;                               // 65536
    float* u_spk = ws + 65536;                       // 65536
    int*   spk_idx = (int*)(ws + 131072);            // 65536 ints
    int*   spk_cnt = (int*)(ws + 196608);            // 16 ints
    float* m_bn  = ws + 200704;                      // 16777216  [B,M,S]
    float* m_s   = m_bn + 16777216;                  // 16777216  [B,S,M]
    float* h_bn  = m_s + 16777216;                   // 25165824  [B*S,HD]

    k_upre<<<dim3(256), dim3(256), 0, stream>>>(x, Wu, Wub, g_u, b_u, mu_u, var_u, u_bn);
    k_ulif<<<dim3(16, 4), dim3(256), 0, stream>>>(u_bn, u_spk);
    k_compact<<<dim3(16), dim3(256), 0, stream>>>(u_spk, spk_idx, spk_cnt);
    k_conv<<<dim3(4096), dim3(256), 0, stream>>>(H, spk_idx, spk_cnt,
                                                 g_m, b_m, mu_m, var_m, m_bn);
    k_mlif<<<dim3(16, 4, 8), dim3(64, 4), 0, stream>>>(m_bn, m_s);
    k_hgemm<<<dim3(512, 3), dim3(256), 0, stream>>>(m_s, x, Wh, Whb,
                                                    g_h, b_h, mu_h, var_h, h_bn);
    k_hlif<<<dim3(16, 6, 8), dim3(64, 4), 0, stream>>>(h_bn, (float*)d_out);
}